// Round 14
// baseline (1482.941 us; speedup 1.0000x reference)
//
#include <hip/hip_runtime.h>

#define T_STEPS 2048
#define BATCH   128
#define HID     100     // LSTM hidden size
#define KP      112     // padded k-extent (multiple of 16)
#define NTH     1024    // 16 waves of 64 -> 4 waves per SIMD

typedef _Float16 h2v __attribute__((ext_vector_type(2)));

// DPP quad_perm broadcast (VALU pipe, immediate ctrl)
template <int CTRL>
__device__ __forceinline__ float dpp_mov(float v) {
    int y = __builtin_amdgcn_update_dpp(0, __float_as_int(v), CTRL, 0xF, 0xF, true);
    return __int_as_float(y);
}

__global__ __launch_bounds__(NTH)
__attribute__((amdgpu_waves_per_eu(4, 4)))   // empirically yields the 64-VGPR bucket here
void lstm_caviar_kernel(
    const float* __restrict__ x,      // [T, B, 1]
    const float* __restrict__ W_ih,   // [400, 1]
    const float* __restrict__ W_hh,   // [400, 100]
    const float* __restrict__ b_ih,   // [400]
    const float* __restrict__ b_hh,   // [400]
    const float* __restrict__ W1,     // [64, 100]
    const float* __restrict__ b1,     // [64]
    const float* __restrict__ W2,     // [1, 64]
    const float* __restrict__ b2,     // [1]
    float* __restrict__ out)          // [1]
{
    __shared__ __align__(16) _Float16 h_buf[2][KP];   // 224 B rows
    __shared__ float x_lds[T_STEPS];
    __shared__ float red_lds[64];

    const int tid  = threadIdx.x;
    const int g    = tid & 3;          // gate owned by this lane (i,f,g,o)
    const int ksub = (tid >> 2) & 1;   // k-half: ksub*56 .. ksub*56+55
    const int j    = tid >> 3;         // (padded) hidden unit, 0..127
    const bool jact = (j < HID);

    // stage batch-0 inputs (x[t,0,0] = flat[t*BATCH]) into LDS once
    for (int t = tid; t < T_STEPS; t += NTH)
        x_lds[t] = x[t * BATCH];
    if (tid < KP) { h_buf[0][tid] = (_Float16)0.0f; h_buf[1][tid] = (_Float16)0.0f; }

    // Preload this lane's 56 weights as 28 packed f16 pairs:
    // k = 56*ksub + 2*q + {0,1}, q=0..27 (zero-padded past k=99; rows j>=100
    // all-zero so their h stays exactly 0 -> no guards in the loop).
    // wi/bias pre-scaled by 0.5 so the 2-lane xor4 reduction sums to exactly 1x.
    const int row = g * HID + (jact ? j : 0);
    const float* wr = W_hh + row * HID;
    h2v w2[28];
    #pragma unroll
    for (int q = 0; q < 28; ++q) {
        const int k0 = 56 * ksub + 2 * q;
        h2v v;
        v.x = (_Float16)((jact && k0 + 0 < HID) ? wr[k0 + 0] : 0.0f);
        v.y = (_Float16)((jact && k0 + 1 < HID) ? wr[k0 + 1] : 0.0f);
        w2[q] = v;
    }
    float wi = jact ? 0.5f * W_ih[row] : 0.0f;
    float bs = jact ? 0.5f * (b_ih[row] + b_hh[row]) : 0.0f;

    const bool is_g = (g == 2);
    float c = 0.0f;
    __syncthreads();

    for (int t = 0; t < T_STEPS; ++t) {
        // light pin: zero instructions when resident; blocks remat/spill
        #pragma unroll
        for (int q = 0; q < 28; ++q)
            asm volatile("" : "+v"(w2[q]));
        asm volatile("" : "+v"(wi), "+v"(bs));

        const _Float16* hb = h_buf[t & 1] + 56 * ksub;
        const float xt = x_lds[t];

        float acc = fmaf(wi, xt, bs);
        #pragma unroll
        for (int p = 0; p < 7; ++p) {
            // 16 B contiguous, 16B-aligned (56*2=112B row offset is 16B-aligned)
            const h2v* hp = (const h2v*)(hb + 8 * p);
            acc = __builtin_amdgcn_fdot2(w2[4*p+0], hp[0], acc, false);
            acc = __builtin_amdgcn_fdot2(w2[4*p+1], hp[1], acc, false);
            acc = __builtin_amdgcn_fdot2(w2[4*p+2], hp[2], acc, false);
            acc = __builtin_amdgcn_fdot2(w2[4*p+3], hp[3], acc, false);
        }

        // reduce across the 2 k-half lanes (xor lane^4): both get the full sum
        acc += __int_as_float(__builtin_amdgcn_ds_swizzle(__float_as_int(acc), 0x101F));

        // this lane activates its own gate (i,f,o: sigmoid; g: tanh = 2*sig(2x)-1)
        const float pre = is_g ? (acc + acc) : acc;
        const float e   = __expf(-pre);
        const float v   = 1.0f / (1.0f + e);
        const float act = is_g ? (v + v - 1.0f) : v;

        // quad broadcast: lanes g=0..3 of this (j,ksub) group share all 4 gates
        const float ig = dpp_mov<0x00>(act);
        const float fg = dpp_mov<0x55>(act);
        const float gg = dpp_mov<0xAA>(act);
        const float og = dpp_mov<0xFF>(act);

        c = fmaf(fg, c, ig * gg);
        const float e2 = __expf(-2.0f * c);
        const float th = 2.0f / (1.0f + e2) - 1.0f;
        const float h  = og * th;

        if ((tid & 7) == 0 && j < KP)
            h_buf[(t + 1) & 1][j] = (_Float16)h;   // j>=100 writes exact 0
        __syncthreads();
    }

    // head: lin = W1 @ h + b1 (64), out = W2 @ lin + b2 (scalar)
    if (tid < 64) {
        const float* r = W1 + tid * HID;
        float a = 0.0f;
        for (int k = 0; k < HID; ++k)
            a = fmaf(r[k], (float)h_buf[0][k], a);   // T even -> final h in buf 0
        red_lds[tid] = a + b1[tid];
    }
    __syncthreads();
    if (tid == 0) {
        float a = b2[0];
        for (int k = 0; k < 64; ++k)
            a = fmaf(W2[k], red_lds[k], a);
        out[0] = a;
    }
}

extern "C" void kernel_launch(void* const* d_in, const int* in_sizes, int n_in,
                              void* d_out, int out_size, void* d_ws, size_t ws_size,
                              hipStream_t stream) {
    lstm_caviar_kernel<<<1, NTH, 0, stream>>>(
        (const float*)d_in[0],  // input_seq
        (const float*)d_in[1],  // W_ih
        (const float*)d_in[2],  // W_hh
        (const float*)d_in[3],  // b_ih
        (const float*)d_in[4],  // b_hh
        (const float*)d_in[5],  // W1
        (const float*)d_in[6],  // b1
        (const float*)d_in[7],  // W2
        (const float*)d_in[8],  // b2
        (float*)d_out);
}